// Round 13
// baseline (683.171 us; speedup 1.0000x reference)
//
#include <hip/hip_runtime.h>
#include <math.h>

#define Bc 2
#define Ec 100000
#define Vc 12500
#define Dc 128
#define Lc 4

typedef __attribute__((ext_vector_type(4))) float f32x4;
typedef __attribute__((ext_vector_type(8))) short short8s;
typedef __attribute__((ext_vector_type(8))) __bf16 bf16x8;

static __device__ __forceinline__ short f2bf(float f) {
    unsigned u = __builtin_bit_cast(unsigned, f);
    unsigned r = (u + 0x7FFFu + ((u >> 16) & 1u)) >> 16;  // RNE
    return (short)r;
}

static __device__ __forceinline__ float bf2f(short s) {
    unsigned u = ((unsigned)(unsigned short)s) << 16;
    return __builtin_bit_cast(float, u);
}

static __device__ __forceinline__ f32x4 mfma16(short8s a, short8s b, f32x4 c) {
    return __builtin_amdgcn_mfma_f32_16x16x32_bf16(
        __builtin_bit_cast(bf16x8, a), __builtin_bit_cast(bf16x8, b), c, 0, 0, 0);
}

// ---------------- timestep embedding MLP (tiny: B=2) ----------------
__global__ void t_emb_kernel(const int* __restrict__ n,
                             const float* __restrict__ te_w1, const float* __restrict__ te_b1,
                             const float* __restrict__ te_w2, const float* __restrict__ te_b2,
                             float* __restrict__ t_emb) {
    const int b = blockIdx.x;
    const int t = threadIdx.x; // 128 threads
    __shared__ float emb[Dc];
    __shared__ float hid[4 * Dc];
    const float nf = (float)n[b];
    const int half = Dc / 2;
    {
        int j = (t < half) ? t : (t - half);
        float freq = expf(-logf(10000.0f) * (float)j / (float)half);
        float arg = nf * freq;
        emb[t] = (t < half) ? sinf(arg) : cosf(arg);
    }
    __syncthreads();
    for (int jj = 0; jj < 4; ++jj) {
        int c = t + jj * Dc;
        float acc = te_b1[c];
        for (int k = 0; k < Dc; ++k) acc += emb[k] * te_w1[k * (4 * Dc) + c];
        hid[c] = acc / (1.0f + expf(-acc));
    }
    __syncthreads();
    float acc = te_b2[t];
    for (int k = 0; k < 4 * Dc; ++k) acc += hid[k] * te_w2[k * Dc + t];
    t_emb[b * Dc + t] = acc;
}

// ---------------- input projection + t_emb add -> h (bf16) ----------------
__global__ void input_proj_kernel(const float* __restrict__ delta,
                                  const float* __restrict__ w_in, const float* __restrict__ b_in,
                                  const float* __restrict__ t_emb,
                                  unsigned short* __restrict__ h) {
    int idx = blockIdx.x * blockDim.x + threadIdx.x;
    const int total = Bc * Ec * (Dc / 4);
    if (idx >= total) return;
    int dq = idx & (Dc / 4 - 1);
    int be = idx >> 5;
    int b = be / Ec;
    const float* dd = delta + (size_t)be * 3;
    float d0 = dd[0], d1 = dd[1], d2 = dd[2];
    float4 acc = ((const float4*)b_in)[dq];
    float4 te = ((const float4*)t_emb)[b * (Dc / 4) + dq];
    float4 w0 = ((const float4*)w_in)[dq];
    float4 w1 = ((const float4*)w_in)[(Dc / 4) + dq];
    float4 w2 = ((const float4*)w_in)[2 * (Dc / 4) + dq];
    acc.x += te.x + d0 * w0.x + d1 * w1.x + d2 * w2.x;
    acc.y += te.y + d0 * w0.y + d1 * w1.y + d2 * w2.y;
    acc.z += te.z + d0 * w0.z + d1 * w1.z + d2 * w2.z;
    acc.w += te.w + d0 * w0.w + d1 * w1.w + d2 * w2.w;
    short4 p;
    p.x = f2bf(acc.x); p.y = f2bf(acc.y); p.z = f2bf(acc.z); p.w = f2bf(acc.w);
    ((short4*)h)[idx] = p;
}

// ---------------- weight pre-convert: fp32 -> bf16 fragment-major ----------------
// w1af[l][half(2)][nt(8)][ks(4)][lane(64)][j(8)]:
//   n = nt*16 + (lane&15), k = half*128 + 32*ks + 8*(lane>>4) + j, val = W1[l][k][n]
// w2f[l][nt(8)][ks(4)][lane(64)][j(8)]: n as above, k = 32*ks+8*(lane>>4)+j, val = W2[l][k][n]
__global__ void convert_w_kernel(const float* __restrict__ W1, const float* __restrict__ W2,
                                 short* __restrict__ w1af, short* __restrict__ w2f) {
    int idx = blockIdx.x * blockDim.x + threadIdx.x;
    if (idx < Lc * 32768) {
        int l = idx >> 15;
        int j = idx & 7;
        int lane = (idx >> 3) & 63;
        int ks = (idx >> 9) & 3;
        int nt = (idx >> 11) & 7;
        int half = (idx >> 14) & 1;
        int r = lane & 15, g = lane >> 4;
        int n = nt * 16 + r;
        int k = half * 128 + 32 * ks + 8 * g + j;
        w1af[idx] = f2bf(W1[((size_t)l * 256 + k) * 128 + n]);
    }
    if (idx < Lc * 16384) {
        int l = idx >> 14;
        int j = idx & 7;
        int lane = (idx >> 3) & 63;
        int ks = (idx >> 9) & 3;
        int nt = (idx >> 11) & 7;
        int r = lane & 15, g = lane >> 4;
        int n = nt * 16 + r;
        int k = 32 * ks + 8 * g + j;
        w2f[idx] = f2bf(W2[((size_t)l * 128 + k) * 128 + n]);
    }
}

// ---------------- CSR build ----------------
__global__ void csr_zero_kernel(int* __restrict__ cnt) {
    int i = blockIdx.x * blockDim.x + threadIdx.x;
    if (i < Vc) cnt[i] = 0;
}

__global__ void csr_count_kernel(const int* __restrict__ src, const int* __restrict__ dst,
                                 int* __restrict__ cnt) {
    int i = blockIdx.x * blockDim.x + threadIdx.x;
    if (i >= 2 * Ec) return;
    int v = (i < Ec) ? src[i] : dst[i - Ec];
    atomicAdd(&cnt[v], 1);
}

__global__ void csr_scan_kernel(const int* __restrict__ cnt,
                                int* __restrict__ off, int* __restrict__ cur) {
    __shared__ int part[256];
    const int t = threadIdx.x;
    const int CH = (Vc + 255) / 256; // 49
    int s = 0;
    for (int j = 0; j < CH; ++j) {
        int i = t * CH + j;
        if (i < Vc) s += cnt[i];
    }
    part[t] = s;
    __syncthreads();
    for (int ofs = 1; ofs < 256; ofs <<= 1) {
        int y = (t >= ofs) ? part[t - ofs] : 0;
        __syncthreads();
        part[t] += y;
        __syncthreads();
    }
    int run = part[t] - s;
    for (int j = 0; j < CH; ++j) {
        int i = t * CH + j;
        if (i < Vc) {
            off[i] = run;
            cur[i] = run;
            run += cnt[i];
        }
    }
    if (t == 255) off[Vc] = run;
}

__global__ void csr_fill_kernel(const int* __restrict__ src, const int* __restrict__ dst,
                                int* __restrict__ cur, int* __restrict__ adj) {
    int i = blockIdx.x * blockDim.x + threadIdx.x;
    if (i >= 2 * Ec) return;
    int e = (i < Ec) ? i : (i - Ec);
    int v = (i < Ec) ? src[e] : dst[e];
    int p = atomicAdd(&cur[v], 1);
    adj[p] = e;
}

// ---------------- gather edges -> vertices (h bf16 in, vf bf16 out) ----------------
// one wave per (b, v); lanes own 2 channels; unroll-8 row loads
__global__ void gather_kernel(const unsigned short* __restrict__ h,
                              const int* __restrict__ off, const int* __restrict__ adj,
                              short* __restrict__ vf) {
    int gw = blockIdx.x * 4 + (threadIdx.x >> 6);
    if (gw >= Bc * Vc) return;
    int b = (gw >= Vc) ? 1 : 0;
    int v = gw - b * Vc;
    int lane = threadIdx.x & 63;
    int o0 = off[v], o1 = off[v + 1];
    const short2* hb = (const short2*)(h + (size_t)b * Ec * Dc);
    float ax[8] = {0.f, 0.f, 0.f, 0.f, 0.f, 0.f, 0.f, 0.f};
    float ay[8] = {0.f, 0.f, 0.f, 0.f, 0.f, 0.f, 0.f, 0.f};
    int j = o0;
    for (; j + 8 <= o1; j += 8) {
        short2 x[8];
        #pragma unroll
        for (int q = 0; q < 8; ++q) x[q] = hb[(size_t)adj[j + q] * 64 + lane];
        #pragma unroll
        for (int q = 0; q < 8; ++q) { ax[q] += bf2f(x[q].x); ay[q] += bf2f(x[q].y); }
    }
    for (; j < o1; ++j) {
        short2 x = hb[(size_t)adj[j] * 64 + lane];
        ax[0] += bf2f(x.x); ay[0] += bf2f(x.y);
    }
    float sx = ((ax[0] + ax[1]) + (ax[2] + ax[3])) + ((ax[4] + ax[5]) + (ax[6] + ax[7]));
    float sy = ((ay[0] + ay[1]) + (ay[2] + ay[3])) + ((ay[4] + ay[5]) + (ay[6] + ay[7]));
    short2 w;
    w.x = f2bf(sx);
    w.y = f2bf(sy);
    ((short2*)vf)[(size_t)gw * (Dc / 2) + lane] = w;
}

// ---------------- per-vertex GEMM1 halves: yA = vf@W1a + b1, yB = vf@W1b ----------
// 256 threads = 4 independent waves; each wave: 32 vertices (two 16-row m-tiles).
__launch_bounds__(256, 4)
__global__ void vertex_gemm_kernel(const short* __restrict__ vf,
                                   const short* __restrict__ w1af, const float* __restrict__ b1,
                                   short* __restrict__ yA, short* __restrict__ yB) {
    const int lane = threadIdx.x & 63;
    const int r = lane & 15;
    const int g = lane >> 4;
    const int vbase = (blockIdx.x * 4 + (threadIdx.x >> 6)) * 32;
    if (vbase >= Bc * Vc) return;

    int vv[2];
    short8s bfrag[2][4];
    #pragma unroll
    for (int mt = 0; mt < 2; ++mt) {
        int v = vbase + mt * 16 + r;
        vv[mt] = v;
        int vcl = (v < Bc * Vc) ? v : (Bc * Vc - 1);
        const short* vrow = vf + (size_t)vcl * Dc;
        #pragma unroll
        for (int ks = 0; ks < 4; ++ks)
            bfrag[mt][ks] = *(const short8s*)(vrow + 32 * ks + 8 * g);
    }

    #pragma unroll
    for (int half = 0; half < 2; ++half) {
        short* y = (half == 0) ? yA : yB;
        f32x4 acc[2][8];
        #pragma unroll
        for (int nt = 0; nt < 8; ++nt) {
            acc[0][nt] = (f32x4){0.f, 0.f, 0.f, 0.f};
            acc[1][nt] = (f32x4){0.f, 0.f, 0.f, 0.f};
            #pragma unroll
            for (int ks = 0; ks < 4; ++ks) {
                short8s afrag = *(const short8s*)(
                    w1af + ((size_t)(((half * 8 + nt) * 4 + ks)) * 64 + lane) * 8);
                acc[0][nt] = mfma16(afrag, bfrag[0][ks], acc[0][nt]);
                acc[1][nt] = mfma16(afrag, bfrag[1][ks], acc[1][nt]);
            }
        }
        #pragma unroll
        for (int mt = 0; mt < 2; ++mt) {
            if (vv[mt] >= Bc * Vc) continue;
            short* yrow = y + (size_t)vv[mt] * Dc;
            #pragma unroll
            for (int nt = 0; nt < 8; ++nt) {
                float4 bb = make_float4(0.f, 0.f, 0.f, 0.f);
                if (half == 0) bb = *(const float4*)&b1[nt * 16 + 4 * g];
                short4 st;
                st.x = f2bf(acc[mt][nt][0] + bb.x);
                st.y = f2bf(acc[mt][nt][1] + bb.y);
                st.z = f2bf(acc[mt][nt][2] + bb.z);
                st.w = f2bf(acc[mt][nt][3] + bb.w);
                *(short4*)(yrow + nt * 16 + 4 * g) = st;
            }
        }
    }
}

// ---------------- fused edge layer: x1 = yA[src]+yB[dst]; LN; silu; GEMM2; LN ------
// 256 threads = 4 independent waves, 32 edges each, ZERO LDS, no barriers.
__launch_bounds__(256, 4)
__global__ void edge_layer_kernel(unsigned short* __restrict__ h,
                                  const short* __restrict__ yA, const short* __restrict__ yB,
                                  const int* __restrict__ src, const int* __restrict__ dst,
                                  const float* __restrict__ ln_g, const float* __restrict__ ln_b,
                                  const short* __restrict__ w2f, const float* __restrict__ b2,
                                  const float* __restrict__ ng, const float* __restrict__ nb,
                                  const float* __restrict__ w_out, const float* __restrict__ b_out,
                                  float* __restrict__ out) {
    const int lane = threadIdx.x & 63;
    const int r = lane & 15;
    const int g = lane >> 4;
    const int wavebase = (blockIdx.x * 4 + (threadIdx.x >> 6)) * 32;
    if (wavebase >= Bc * Ec) return;

    const short *arow[2], *brow[2];
    #pragma unroll
    for (int mt = 0; mt < 2; ++mt) {
        int eg = wavebase + mt * 16 + r;
        int bb = (eg >= Ec) ? 1 : 0;
        int e = eg - bb * Ec;
        arow[mt] = yA + ((size_t)(bb * Vc + src[e])) * Dc;
        brow[mt] = yB + ((size_t)(bb * Vc + dst[e])) * Dc;
    }

    // preload all 16 row-slices (loads in flight together)
    short8s sa[2][4], sb[2][4];
    #pragma unroll
    for (int mt = 0; mt < 2; ++mt)
        #pragma unroll
        for (int ks = 0; ks < 4; ++ks) {
            sa[mt][ks] = *(const short8s*)(arow[mt] + 32 * ks + 8 * g);
            sb[mt][ks] = *(const short8s*)(brow[mt] + 32 * ks + 8 * g);
        }

    const bool last = (w_out != nullptr);

    #pragma unroll
    for (int mt = 0; mt < 2; ++mt) {
        const int eg = wavebase + mt * 16 + r;
        unsigned short* hrow = h + (size_t)eg * Dc;

        // prefetch residual fragments (consumed after GEMM2)
        short4 hpre[8];
        #pragma unroll
        for (int nt = 0; nt < 8; ++nt)
            hpre[nt] = *(const short4*)(hrow + nt * 16 + 4 * g);

        // ---- x1 = yA[src] + yB[dst]; LN over 128 (4 lanes share a row); silu
        float x1v[4][8];
        float s = 0.f, ss = 0.f;
        #pragma unroll
        for (int ks = 0; ks < 4; ++ks)
            #pragma unroll
            for (int j = 0; j < 8; ++j) {
                float v = bf2f(sa[mt][ks][j]) + bf2f(sb[mt][ks][j]);
                x1v[ks][j] = v;
                s += v; ss += v * v;
            }
        s += __shfl_xor(s, 16); ss += __shfl_xor(ss, 16);
        s += __shfl_xor(s, 32); ss += __shfl_xor(ss, 32);
        float mean = s * (1.0f / Dc);
        float var = ss * (1.0f / Dc) - mean * mean;
        float rstd = rsqrtf(var + 1e-5f);

        short8s bfrag[4];
        #pragma unroll
        for (int ks = 0; ks < 4; ++ks) {
            const float4 lg0 = *(const float4*)&ln_g[32 * ks + 8 * g];
            const float4 lg1 = *(const float4*)&ln_g[32 * ks + 8 * g + 4];
            const float4 lb0 = *(const float4*)&ln_b[32 * ks + 8 * g];
            const float4 lb1 = *(const float4*)&ln_b[32 * ks + 8 * g + 4];
            #pragma unroll
            for (int j = 0; j < 8; ++j) {
                float gg = (j < 4) ? ((j == 0) ? lg0.x : (j == 1) ? lg0.y : (j == 2) ? lg0.z : lg0.w)
                                   : ((j == 4) ? lg1.x : (j == 5) ? lg1.y : (j == 6) ? lg1.z : lg1.w);
                float bb = (j < 4) ? ((j == 0) ? lb0.x : (j == 1) ? lb0.y : (j == 2) ? lb0.z : lb0.w)
                                   : ((j == 4) ? lb1.x : (j == 5) ? lb1.y : (j == 6) ? lb1.z : lb1.w);
                float xh = (x1v[ks][j] - mean) * rstd * gg + bb;
                float o = xh / (1.0f + __expf(-xh));
                bfrag[ks][j] = f2bf(o);
            }
        }

        // ---- GEMM2t: x2^T = W2^T (128x128) @ x1^T (128x16)
        f32x4 acc2[8];
        #pragma unroll
        for (int nt = 0; nt < 8; ++nt) {
            acc2[nt] = (f32x4){0.f, 0.f, 0.f, 0.f};
            #pragma unroll
            for (int ks = 0; ks < 4; ++ks) {
                short8s afrag = *(const short8s*)(w2f + ((size_t)(nt * 4 + ks) * 64 + lane) * 8);
                acc2[nt] = mfma16(afrag, bfrag[ks], acc2[nt]);
            }
        }

        // ---- bias + residual + LN -> h (or fused out-proj on last layer)
        float s2 = 0.f, ss2 = 0.f;
        #pragma unroll
        for (int nt = 0; nt < 8; ++nt) {
            const float4 bb = *(const float4*)&b2[nt * 16 + 4 * g];
            acc2[nt][0] += bb.x + bf2f(hpre[nt].x);
            acc2[nt][1] += bb.y + bf2f(hpre[nt].y);
            acc2[nt][2] += bb.z + bf2f(hpre[nt].z);
            acc2[nt][3] += bb.w + bf2f(hpre[nt].w);
            #pragma unroll
            for (int i = 0; i < 4; ++i) { float v = acc2[nt][i]; s2 += v; ss2 += v * v; }
        }
        s2 += __shfl_xor(s2, 16); ss2 += __shfl_xor(ss2, 16);
        s2 += __shfl_xor(s2, 32); ss2 += __shfl_xor(ss2, 32);
        float mean2 = s2 * (1.0f / Dc);
        float var2 = ss2 * (1.0f / Dc) - mean2 * mean2;
        float rstd2 = rsqrtf(var2 + 1e-5f);
        if (!last) {
            #pragma unroll
            for (int nt = 0; nt < 8; ++nt) {
                const float4 gv = *(const float4*)&ng[nt * 16 + 4 * g];
                const float4 bv = *(const float4*)&nb[nt * 16 + 4 * g];
                short4 o;
                o.x = f2bf((acc2[nt][0] - mean2) * rstd2 * gv.x + bv.x);
                o.y = f2bf((acc2[nt][1] - mean2) * rstd2 * gv.y + bv.y);
                o.z = f2bf((acc2[nt][2] - mean2) * rstd2 * gv.z + bv.z);
                o.w = f2bf((acc2[nt][3] - mean2) * rstd2 * gv.w + bv.w);
                *(short4*)(hrow + nt * 16 + 4 * g) = o;
            }
        } else {
            float a0 = 0.f, a1 = 0.f, a2 = 0.f;
            #pragma unroll
            for (int nt = 0; nt < 8; ++nt) {
                const float4 gv = *(const float4*)&ng[nt * 16 + 4 * g];
                const float4 bv = *(const float4*)&nb[nt * 16 + 4 * g];
                #pragma unroll
                for (int i = 0; i < 4; ++i) {
                    float gg = (i == 0) ? gv.x : (i == 1) ? gv.y : (i == 2) ? gv.z : gv.w;
                    float bb = (i == 0) ? bv.x : (i == 1) ? bv.y : (i == 2) ? bv.z : bv.w;
                    float y = (acc2[nt][i] - mean2) * rstd2 * gg + bb;
                    int nidx = nt * 16 + 4 * g + i;
                    a0 += y * w_out[nidx * 3 + 0];
                    a1 += y * w_out[nidx * 3 + 1];
                    a2 += y * w_out[nidx * 3 + 2];
                }
            }
            a0 += __shfl_xor(a0, 16); a1 += __shfl_xor(a1, 16); a2 += __shfl_xor(a2, 16);
            a0 += __shfl_xor(a0, 32); a1 += __shfl_xor(a1, 32); a2 += __shfl_xor(a2, 32);
            if (g == 0) {
                out[(size_t)eg * 3 + 0] = a0 + b_out[0];
                out[(size_t)eg * 3 + 1] = a1 + b_out[1];
                out[(size_t)eg * 3 + 2] = a2 + b_out[2];
            }
        }
    }
}

extern "C" void kernel_launch(void* const* d_in, const int* in_sizes, int n_in,
                              void* d_out, int out_size, void* d_ws, size_t ws_size,
                              hipStream_t stream) {
    const float* delta = (const float*)d_in[0];
    const int* n = (const int*)d_in[1];
    const int* edge_index = (const int*)d_in[2];
    const float* w_in = (const float*)d_in[4];
    const float* b_in = (const float*)d_in[5];
    const float* W1 = (const float*)d_in[6];
    const float* b1 = (const float*)d_in[7];
    const float* ln_g = (const float*)d_in[8];
    const float* ln_b = (const float*)d_in[9];
    const float* W2 = (const float*)d_in[10];
    const float* b2 = (const float*)d_in[11];
    const float* ng = (const float*)d_in[12];
    const float* nb = (const float*)d_in[13];
    const float* te_w1 = (const float*)d_in[14];
    const float* te_b1 = (const float*)d_in[15];
    const float* te_w2 = (const float*)d_in[16];
    const float* te_b2 = (const float*)d_in[17];
    const float* w_out = (const float*)d_in[18];
    const float* b_out = (const float*)d_in[19];
    float* out = (float*)d_out;

    // ---- workspace layout (all 256B-aligned) ----
    char* ws = (char*)d_ws;
    size_t o = 0;
    float* t_emb = (float*)(ws + o); o += 1024;
    unsigned short* h = (unsigned short*)(ws + o); o += (size_t)Bc * Ec * Dc * 2;  // 51.2 MB
    short* vf    = (short*)(ws + o); o += (size_t)Bc * Vc * Dc * 2;                // 6.4 MB
    short* yA    = (short*)(ws + o); o += (size_t)Bc * Vc * Dc * 2;                // 6.4 MB
    short* yB    = (short*)(ws + o); o += (size_t)Bc * Vc * Dc * 2;                // 6.4 MB
    short* w1af  = (short*)(ws + o); o += (size_t)Lc * 32768 * 2;
    short* w2f   = (short*)(ws + o); o += (size_t)Lc * 16384 * 2;
    int* cnt     = (int*)(ws + o);   o += ((size_t)Vc * 4 + 255) / 256 * 256;
    int* off     = (int*)(ws + o);   o += ((size_t)(Vc + 1) * 4 + 255) / 256 * 256;
    int* cur     = (int*)(ws + o);   o += ((size_t)Vc * 4 + 255) / 256 * 256;
    int* adj     = (int*)(ws + o);   o += (size_t)2 * Ec * 4;                      // 800 KB

    const int* src = edge_index;
    const int* dst = edge_index + Ec;

    t_emb_kernel<<<Bc, Dc, 0, stream>>>(n, te_w1, te_b1, te_w2, te_b2, t_emb);
    convert_w_kernel<<<(Lc * 32768 + 255) / 256, 256, 0, stream>>>(W1, W2, w1af, w2f);

    {
        int total = Bc * Ec * (Dc / 4);
        input_proj_kernel<<<(total + 255) / 256, 256, 0, stream>>>(delta, w_in, b_in, t_emb, h);
    }

    // CSR build (once per call)
    csr_zero_kernel<<<(Vc + 255) / 256, 256, 0, stream>>>(cnt);
    csr_count_kernel<<<(2 * Ec + 255) / 256, 256, 0, stream>>>(src, dst, cnt);
    csr_scan_kernel<<<1, 256, 0, stream>>>(cnt, off, cur);
    csr_fill_kernel<<<(2 * Ec + 255) / 256, 256, 0, stream>>>(src, dst, cur, adj);

    const int vblocks = (Bc * Vc + 127) / 128;   // 4 waves x 32 vertices
    const int eblocks = (Bc * Ec + 127) / 128;   // 4 waves x 32 edges
    for (int i = 0; i < Lc; ++i) {
        gather_kernel<<<(Bc * Vc + 3) / 4, 256, 0, stream>>>(h, off, adj, vf);
        vertex_gemm_kernel<<<vblocks, 256, 0, stream>>>(
            vf, w1af + (size_t)i * 32768, b1 + i * Dc, yA, yB);
        edge_layer_kernel<<<eblocks, 256, 0, stream>>>(
            h, yA, yB, src, dst,
            ln_g + i * Dc, ln_b + i * Dc,
            w2f + (size_t)i * 16384, b2 + i * Dc,
            ng + i * Dc, nb + i * Dc,
            (i == Lc - 1) ? w_out : nullptr, b_out, out);
    }
}

// Round 14
// 600.349 us; speedup vs baseline: 1.1380x; 1.1380x over previous
//
#include <hip/hip_runtime.h>
#include <math.h>

#define Bc 2
#define Ec 100000
#define Vc 12500
#define Dc 128
#define Lc 4

typedef __attribute__((ext_vector_type(4))) float f32x4;
typedef __attribute__((ext_vector_type(8))) short short8s;
typedef __attribute__((ext_vector_type(8))) __bf16 bf16x8;

static __device__ __forceinline__ short f2bf(float f) {
    unsigned u = __builtin_bit_cast(unsigned, f);
    unsigned r = (u + 0x7FFFu + ((u >> 16) & 1u)) >> 16;  // RNE
    return (short)r;
}

static __device__ __forceinline__ float bf2f(short s) {
    unsigned u = ((unsigned)(unsigned short)s) << 16;
    return __builtin_bit_cast(float, u);
}

static __device__ __forceinline__ f32x4 mfma16(short8s a, short8s b, f32x4 c) {
    return __builtin_amdgcn_mfma_f32_16x16x32_bf16(
        __builtin_bit_cast(bf16x8, a), __builtin_bit_cast(bf16x8, b), c, 0, 0, 0);
}

// ---------------- timestep embedding MLP (tiny: B=2) ----------------
__global__ void t_emb_kernel(const int* __restrict__ n,
                             const float* __restrict__ te_w1, const float* __restrict__ te_b1,
                             const float* __restrict__ te_w2, const float* __restrict__ te_b2,
                             float* __restrict__ t_emb) {
    const int b = blockIdx.x;
    const int t = threadIdx.x; // 128 threads
    __shared__ float emb[Dc];
    __shared__ float hid[4 * Dc];
    const float nf = (float)n[b];
    const int half = Dc / 2;
    {
        int j = (t < half) ? t : (t - half);
        float freq = expf(-logf(10000.0f) * (float)j / (float)half);
        float arg = nf * freq;
        emb[t] = (t < half) ? sinf(arg) : cosf(arg);
    }
    __syncthreads();
    for (int jj = 0; jj < 4; ++jj) {
        int c = t + jj * Dc;
        float acc = te_b1[c];
        for (int k = 0; k < Dc; ++k) acc += emb[k] * te_w1[k * (4 * Dc) + c];
        hid[c] = acc / (1.0f + expf(-acc));
    }
    __syncthreads();
    float acc = te_b2[t];
    for (int k = 0; k < 4 * Dc; ++k) acc += hid[k] * te_w2[k * Dc + t];
    t_emb[b * Dc + t] = acc;
}

// ---------------- input projection + t_emb add -> h (bf16) ----------------
__global__ void input_proj_kernel(const float* __restrict__ delta,
                                  const float* __restrict__ w_in, const float* __restrict__ b_in,
                                  const float* __restrict__ t_emb,
                                  unsigned short* __restrict__ h) {
    int idx = blockIdx.x * blockDim.x + threadIdx.x;
    const int total = Bc * Ec * (Dc / 4);
    if (idx >= total) return;
    int dq = idx & (Dc / 4 - 1);
    int be = idx >> 5;
    int b = be / Ec;
    const float* dd = delta + (size_t)be * 3;
    float d0 = dd[0], d1 = dd[1], d2 = dd[2];
    float4 acc = ((const float4*)b_in)[dq];
    float4 te = ((const float4*)t_emb)[b * (Dc / 4) + dq];
    float4 w0 = ((const float4*)w_in)[dq];
    float4 w1 = ((const float4*)w_in)[(Dc / 4) + dq];
    float4 w2 = ((const float4*)w_in)[2 * (Dc / 4) + dq];
    acc.x += te.x + d0 * w0.x + d1 * w1.x + d2 * w2.x;
    acc.y += te.y + d0 * w0.y + d1 * w1.y + d2 * w2.y;
    acc.z += te.z + d0 * w0.z + d1 * w1.z + d2 * w2.z;
    acc.w += te.w + d0 * w0.w + d1 * w1.w + d2 * w2.w;
    short4 p;
    p.x = f2bf(acc.x); p.y = f2bf(acc.y); p.z = f2bf(acc.z); p.w = f2bf(acc.w);
    ((short4*)h)[idx] = p;
}

// ---------------- weight pre-convert: fp32 -> bf16 fragment-major ----------------
// w1af[l][half(2)][nt(8)][ks(4)][lane(64)][j(8)]:
//   n = nt*16 + (lane&15), k = half*128 + 32*ks + 8*(lane>>4) + j, val = W1[l][k][n]
// w2f[l][nt(8)][ks(4)][lane(64)][j(8)]: n as above, k = 32*ks+8*(lane>>4)+j, val = W2[l][k][n]
__global__ void convert_w_kernel(const float* __restrict__ W1, const float* __restrict__ W2,
                                 short* __restrict__ w1af, short* __restrict__ w2f) {
    int idx = blockIdx.x * blockDim.x + threadIdx.x;
    if (idx < Lc * 32768) {
        int l = idx >> 15;
        int j = idx & 7;
        int lane = (idx >> 3) & 63;
        int ks = (idx >> 9) & 3;
        int nt = (idx >> 11) & 7;
        int half = (idx >> 14) & 1;
        int r = lane & 15, g = lane >> 4;
        int n = nt * 16 + r;
        int k = half * 128 + 32 * ks + 8 * g + j;
        w1af[idx] = f2bf(W1[((size_t)l * 256 + k) * 128 + n]);
    }
    if (idx < Lc * 16384) {
        int l = idx >> 14;
        int j = idx & 7;
        int lane = (idx >> 3) & 63;
        int ks = (idx >> 9) & 3;
        int nt = (idx >> 11) & 7;
        int r = lane & 15, g = lane >> 4;
        int n = nt * 16 + r;
        int k = 32 * ks + 8 * g + j;
        w2f[idx] = f2bf(W2[((size_t)l * 128 + k) * 128 + n]);
    }
}

// ---------------- CSR build ----------------
__global__ void csr_zero_kernel(int* __restrict__ cnt) {
    int i = blockIdx.x * blockDim.x + threadIdx.x;
    if (i < Vc) cnt[i] = 0;
}

__global__ void csr_count_kernel(const int* __restrict__ src, const int* __restrict__ dst,
                                 int* __restrict__ cnt) {
    int i = blockIdx.x * blockDim.x + threadIdx.x;
    if (i >= 2 * Ec) return;
    int v = (i < Ec) ? src[i] : dst[i - Ec];
    atomicAdd(&cnt[v], 1);
}

__global__ void csr_scan_kernel(const int* __restrict__ cnt,
                                int* __restrict__ off, int* __restrict__ cur) {
    __shared__ int part[256];
    const int t = threadIdx.x;
    const int CH = (Vc + 255) / 256; // 49
    int s = 0;
    for (int j = 0; j < CH; ++j) {
        int i = t * CH + j;
        if (i < Vc) s += cnt[i];
    }
    part[t] = s;
    __syncthreads();
    for (int ofs = 1; ofs < 256; ofs <<= 1) {
        int y = (t >= ofs) ? part[t - ofs] : 0;
        __syncthreads();
        part[t] += y;
        __syncthreads();
    }
    int run = part[t] - s;
    for (int j = 0; j < CH; ++j) {
        int i = t * CH + j;
        if (i < Vc) {
            off[i] = run;
            cur[i] = run;
            run += cnt[i];
        }
    }
    if (t == 255) off[Vc] = run;
}

__global__ void csr_fill_kernel(const int* __restrict__ src, const int* __restrict__ dst,
                                int* __restrict__ cur, int* __restrict__ adj) {
    int i = blockIdx.x * blockDim.x + threadIdx.x;
    if (i >= 2 * Ec) return;
    int e = (i < Ec) ? i : (i - Ec);
    int v = (i < Ec) ? src[e] : dst[e];
    int p = atomicAdd(&cur[v], 1);
    adj[p] = e;
}

// ---------------- gather edges -> vertices (h bf16 in, vf bf16 out) ----------------
// one wave per (b, v); lanes own 2 channels; unroll-8 row loads
__global__ void gather_kernel(const unsigned short* __restrict__ h,
                              const int* __restrict__ off, const int* __restrict__ adj,
                              short* __restrict__ vf) {
    int gw = blockIdx.x * 4 + (threadIdx.x >> 6);
    if (gw >= Bc * Vc) return;
    int b = (gw >= Vc) ? 1 : 0;
    int v = gw - b * Vc;
    int lane = threadIdx.x & 63;
    int o0 = off[v], o1 = off[v + 1];
    const short2* hb = (const short2*)(h + (size_t)b * Ec * Dc);
    float ax[8] = {0.f, 0.f, 0.f, 0.f, 0.f, 0.f, 0.f, 0.f};
    float ay[8] = {0.f, 0.f, 0.f, 0.f, 0.f, 0.f, 0.f, 0.f};
    int j = o0;
    for (; j + 8 <= o1; j += 8) {
        short2 x[8];
        #pragma unroll
        for (int q = 0; q < 8; ++q) x[q] = hb[(size_t)adj[j + q] * 64 + lane];
        #pragma unroll
        for (int q = 0; q < 8; ++q) { ax[q] += bf2f(x[q].x); ay[q] += bf2f(x[q].y); }
    }
    for (; j < o1; ++j) {
        short2 x = hb[(size_t)adj[j] * 64 + lane];
        ax[0] += bf2f(x.x); ay[0] += bf2f(x.y);
    }
    float sx = ((ax[0] + ax[1]) + (ax[2] + ax[3])) + ((ax[4] + ax[5]) + (ax[6] + ax[7]));
    float sy = ((ay[0] + ay[1]) + (ay[2] + ay[3])) + ((ay[4] + ay[5]) + (ay[6] + ay[7]));
    short2 w;
    w.x = f2bf(sx);
    w.y = f2bf(sy);
    ((short2*)vf)[(size_t)gw * (Dc / 2) + lane] = w;
}

// ---------------- per-vertex GEMM1 halves: yA = vf@W1a + b1, yB = vf@W1b ----------
// 128 threads = 2 independent waves; each wave: 32 vertices (two 16-row m-tiles).
__launch_bounds__(128, 3)
__global__ void vertex_gemm_kernel(const short* __restrict__ vf,
                                   const short* __restrict__ w1af, const float* __restrict__ b1,
                                   short* __restrict__ yA, short* __restrict__ yB) {
    const int lane = threadIdx.x & 63;
    const int r = lane & 15;
    const int g = lane >> 4;
    const int vbase = (blockIdx.x * 2 + (threadIdx.x >> 6)) * 32;
    if (vbase >= Bc * Vc) return;

    int vv[2];
    short8s bfrag[2][4];
    #pragma unroll
    for (int mt = 0; mt < 2; ++mt) {
        int v = vbase + mt * 16 + r;
        vv[mt] = v;
        int vcl = (v < Bc * Vc) ? v : (Bc * Vc - 1);
        const short* vrow = vf + (size_t)vcl * Dc;
        #pragma unroll
        for (int ks = 0; ks < 4; ++ks)
            bfrag[mt][ks] = *(const short8s*)(vrow + 32 * ks + 8 * g);
    }

    #pragma unroll
    for (int half = 0; half < 2; ++half) {
        short* y = (half == 0) ? yA : yB;
        f32x4 acc[2][8];
        #pragma unroll
        for (int nt = 0; nt < 8; ++nt) {
            acc[0][nt] = (f32x4){0.f, 0.f, 0.f, 0.f};
            acc[1][nt] = (f32x4){0.f, 0.f, 0.f, 0.f};
            #pragma unroll
            for (int ks = 0; ks < 4; ++ks) {
                short8s afrag = *(const short8s*)(
                    w1af + ((size_t)(((half * 8 + nt) * 4 + ks)) * 64 + lane) * 8);
                acc[0][nt] = mfma16(afrag, bfrag[0][ks], acc[0][nt]);
                acc[1][nt] = mfma16(afrag, bfrag[1][ks], acc[1][nt]);
            }
        }
        #pragma unroll
        for (int mt = 0; mt < 2; ++mt) {
            if (vv[mt] >= Bc * Vc) continue;
            short* yrow = y + (size_t)vv[mt] * Dc;
            #pragma unroll
            for (int nt = 0; nt < 8; ++nt) {
                float4 bb = make_float4(0.f, 0.f, 0.f, 0.f);
                if (half == 0) bb = *(const float4*)&b1[nt * 16 + 4 * g];
                short4 st;
                st.x = f2bf(acc[mt][nt][0] + bb.x);
                st.y = f2bf(acc[mt][nt][1] + bb.y);
                st.z = f2bf(acc[mt][nt][2] + bb.z);
                st.w = f2bf(acc[mt][nt][3] + bb.w);
                *(short4*)(yrow + nt * 16 + 4 * g) = st;
            }
        }
    }
}

// ---------------- fused edge layer: x1 = yA[src]+yB[dst]; LN; silu; GEMM2; LN ------
// 128 threads = 2 independent waves, 32 edges each, ZERO LDS, no barriers.
__launch_bounds__(128, 3)
__global__ void edge_layer_kernel(unsigned short* __restrict__ h,
                                  const short* __restrict__ yA, const short* __restrict__ yB,
                                  const int* __restrict__ src, const int* __restrict__ dst,
                                  const float* __restrict__ ln_g, const float* __restrict__ ln_b,
                                  const short* __restrict__ w2f, const float* __restrict__ b2,
                                  const float* __restrict__ ng, const float* __restrict__ nb,
                                  const float* __restrict__ w_out, const float* __restrict__ b_out,
                                  float* __restrict__ out) {
    const int lane = threadIdx.x & 63;
    const int r = lane & 15;
    const int g = lane >> 4;
    const int wavebase = (blockIdx.x * 2 + (threadIdx.x >> 6)) * 32;
    if (wavebase >= Bc * Ec) return;

    const short *arow[2], *brow[2];
    #pragma unroll
    for (int mt = 0; mt < 2; ++mt) {
        int eg = wavebase + mt * 16 + r;
        int bb = (eg >= Ec) ? 1 : 0;
        int e = eg - bb * Ec;
        arow[mt] = yA + ((size_t)(bb * Vc + src[e])) * Dc;
        brow[mt] = yB + ((size_t)(bb * Vc + dst[e])) * Dc;
    }

    // preload all 16 row-slices (loads in flight together)
    short8s sa[2][4], sb[2][4];
    #pragma unroll
    for (int mt = 0; mt < 2; ++mt)
        #pragma unroll
        for (int ks = 0; ks < 4; ++ks) {
            sa[mt][ks] = *(const short8s*)(arow[mt] + 32 * ks + 8 * g);
            sb[mt][ks] = *(const short8s*)(brow[mt] + 32 * ks + 8 * g);
        }

    const bool last = (w_out != nullptr);

    #pragma unroll
    for (int mt = 0; mt < 2; ++mt) {
        const int eg = wavebase + mt * 16 + r;
        unsigned short* hrow = h + (size_t)eg * Dc;

        // prefetch residual fragments (consumed after GEMM2)
        short4 hpre[8];
        #pragma unroll
        for (int nt = 0; nt < 8; ++nt)
            hpre[nt] = *(const short4*)(hrow + nt * 16 + 4 * g);

        // ---- x1 = yA[src] + yB[dst]; LN over 128 (4 lanes share a row); silu
        float x1v[4][8];
        float s = 0.f, ss = 0.f;
        #pragma unroll
        for (int ks = 0; ks < 4; ++ks)
            #pragma unroll
            for (int j = 0; j < 8; ++j) {
                float v = bf2f(sa[mt][ks][j]) + bf2f(sb[mt][ks][j]);
                x1v[ks][j] = v;
                s += v; ss += v * v;
            }
        s += __shfl_xor(s, 16); ss += __shfl_xor(ss, 16);
        s += __shfl_xor(s, 32); ss += __shfl_xor(ss, 32);
        float mean = s * (1.0f / Dc);
        float var = ss * (1.0f / Dc) - mean * mean;
        float rstd = rsqrtf(var + 1e-5f);

        short8s bfrag[4];
        #pragma unroll
        for (int ks = 0; ks < 4; ++ks) {
            const float4 lg0 = *(const float4*)&ln_g[32 * ks + 8 * g];
            const float4 lg1 = *(const float4*)&ln_g[32 * ks + 8 * g + 4];
            const float4 lb0 = *(const float4*)&ln_b[32 * ks + 8 * g];
            const float4 lb1 = *(const float4*)&ln_b[32 * ks + 8 * g + 4];
            #pragma unroll
            for (int j = 0; j < 8; ++j) {
                float gg = (j < 4) ? ((j == 0) ? lg0.x : (j == 1) ? lg0.y : (j == 2) ? lg0.z : lg0.w)
                                   : ((j == 4) ? lg1.x : (j == 5) ? lg1.y : (j == 6) ? lg1.z : lg1.w);
                float bb = (j < 4) ? ((j == 0) ? lb0.x : (j == 1) ? lb0.y : (j == 2) ? lb0.z : lb0.w)
                                   : ((j == 4) ? lb1.x : (j == 5) ? lb1.y : (j == 6) ? lb1.z : lb1.w);
                float xh = (x1v[ks][j] - mean) * rstd * gg + bb;
                float o = xh * __builtin_amdgcn_rcpf(1.0f + __expf(-xh));  // fast silu
                bfrag[ks][j] = f2bf(o);
            }
        }

        // ---- GEMM2t: x2^T = W2^T (128x128) @ x1^T (128x16)
        f32x4 acc2[8];
        #pragma unroll
        for (int nt = 0; nt < 8; ++nt) {
            acc2[nt] = (f32x4){0.f, 0.f, 0.f, 0.f};
            #pragma unroll
            for (int ks = 0; ks < 4; ++ks) {
                short8s afrag = *(const short8s*)(w2f + ((size_t)(nt * 4 + ks) * 64 + lane) * 8);
                acc2[nt] = mfma16(afrag, bfrag[ks], acc2[nt]);
            }
        }

        // ---- bias + residual + LN -> h (or fused out-proj on last layer)
        float s2 = 0.f, ss2 = 0.f;
        #pragma unroll
        for (int nt = 0; nt < 8; ++nt) {
            const float4 bb = *(const float4*)&b2[nt * 16 + 4 * g];
            acc2[nt][0] += bb.x + bf2f(hpre[nt].x);
            acc2[nt][1] += bb.y + bf2f(hpre[nt].y);
            acc2[nt][2] += bb.z + bf2f(hpre[nt].z);
            acc2[nt][3] += bb.w + bf2f(hpre[nt].w);
            #pragma unroll
            for (int i = 0; i < 4; ++i) { float v = acc2[nt][i]; s2 += v; ss2 += v * v; }
        }
        s2 += __shfl_xor(s2, 16); ss2 += __shfl_xor(ss2, 16);
        s2 += __shfl_xor(s2, 32); ss2 += __shfl_xor(ss2, 32);
        float mean2 = s2 * (1.0f / Dc);
        float var2 = ss2 * (1.0f / Dc) - mean2 * mean2;
        float rstd2 = rsqrtf(var2 + 1e-5f);
        if (!last) {
            #pragma unroll
            for (int nt = 0; nt < 8; ++nt) {
                const float4 gv = *(const float4*)&ng[nt * 16 + 4 * g];
                const float4 bv = *(const float4*)&nb[nt * 16 + 4 * g];
                short4 o;
                o.x = f2bf((acc2[nt][0] - mean2) * rstd2 * gv.x + bv.x);
                o.y = f2bf((acc2[nt][1] - mean2) * rstd2 * gv.y + bv.y);
                o.z = f2bf((acc2[nt][2] - mean2) * rstd2 * gv.z + bv.z);
                o.w = f2bf((acc2[nt][3] - mean2) * rstd2 * gv.w + bv.w);
                *(short4*)(hrow + nt * 16 + 4 * g) = o;
            }
        } else {
            float a0 = 0.f, a1 = 0.f, a2 = 0.f;
            #pragma unroll
            for (int nt = 0; nt < 8; ++nt) {
                const float4 gv = *(const float4*)&ng[nt * 16 + 4 * g];
                const float4 bv = *(const float4*)&nb[nt * 16 + 4 * g];
                #pragma unroll
                for (int i = 0; i < 4; ++i) {
                    float gg = (i == 0) ? gv.x : (i == 1) ? gv.y : (i == 2) ? gv.z : gv.w;
                    float bb = (i == 0) ? bv.x : (i == 1) ? bv.y : (i == 2) ? bv.z : bv.w;
                    float y = (acc2[nt][i] - mean2) * rstd2 * gg + bb;
                    int nidx = nt * 16 + 4 * g + i;
                    a0 += y * w_out[nidx * 3 + 0];
                    a1 += y * w_out[nidx * 3 + 1];
                    a2 += y * w_out[nidx * 3 + 2];
                }
            }
            a0 += __shfl_xor(a0, 16); a1 += __shfl_xor(a1, 16); a2 += __shfl_xor(a2, 16);
            a0 += __shfl_xor(a0, 32); a1 += __shfl_xor(a1, 32); a2 += __shfl_xor(a2, 32);
            if (g == 0) {
                out[(size_t)eg * 3 + 0] = a0 + b_out[0];
                out[(size_t)eg * 3 + 1] = a1 + b_out[1];
                out[(size_t)eg * 3 + 2] = a2 + b_out[2];
            }
        }
    }
}

extern "C" void kernel_launch(void* const* d_in, const int* in_sizes, int n_in,
                              void* d_out, int out_size, void* d_ws, size_t ws_size,
                              hipStream_t stream) {
    const float* delta = (const float*)d_in[0];
    const int* n = (const int*)d_in[1];
    const int* edge_index = (const int*)d_in[2];
    const float* w_in = (const float*)d_in[4];
    const float* b_in = (const float*)d_in[5];
    const float* W1 = (const float*)d_in[6];
    const float* b1 = (const float*)d_in[7];
    const float* ln_g = (const float*)d_in[8];
    const float* ln_b = (const float*)d_in[9];
    const float* W2 = (const float*)d_in[10];
    const float* b2 = (const float*)d_in[11];
    const float* ng = (const float*)d_in[12];
    const float* nb = (const float*)d_in[13];
    const float* te_w1 = (const float*)d_in[14];
    const float* te_b1 = (const float*)d_in[15];
    const float* te_w2 = (const float*)d_in[16];
    const float* te_b2 = (const float*)d_in[17];
    const float* w_out = (const float*)d_in[18];
    const float* b_out = (const float*)d_in[19];
    float* out = (float*)d_out;

    // ---- workspace layout (all 256B-aligned) ----
    char* ws = (char*)d_ws;
    size_t o = 0;
    float* t_emb = (float*)(ws + o); o += 1024;
    unsigned short* h = (unsigned short*)(ws + o); o += (size_t)Bc * Ec * Dc * 2;  // 51.2 MB
    short* vf    = (short*)(ws + o); o += (size_t)Bc * Vc * Dc * 2;                // 6.4 MB
    short* yA    = (short*)(ws + o); o += (size_t)Bc * Vc * Dc * 2;                // 6.4 MB
    short* yB    = (short*)(ws + o); o += (size_t)Bc * Vc * Dc * 2;                // 6.4 MB
    short* w1af  = (short*)(ws + o); o += (size_t)Lc * 32768 * 2;
    short* w2f   = (short*)(ws + o); o += (size_t)Lc * 16384 * 2;
    int* cnt     = (int*)(ws + o);   o += ((size_t)Vc * 4 + 255) / 256 * 256;
    int* off     = (int*)(ws + o);   o += ((size_t)(Vc + 1) * 4 + 255) / 256 * 256;
    int* cur     = (int*)(ws + o);   o += ((size_t)Vc * 4 + 255) / 256 * 256;
    int* adj     = (int*)(ws + o);   o += (size_t)2 * Ec * 4;                      // 800 KB

    const int* src = edge_index;
    const int* dst = edge_index + Ec;

    t_emb_kernel<<<Bc, Dc, 0, stream>>>(n, te_w1, te_b1, te_w2, te_b2, t_emb);
    convert_w_kernel<<<(Lc * 32768 + 255) / 256, 256, 0, stream>>>(W1, W2, w1af, w2f);

    {
        int total = Bc * Ec * (Dc / 4);
        input_proj_kernel<<<(total + 255) / 256, 256, 0, stream>>>(delta, w_in, b_in, t_emb, h);
    }

    // CSR build (once per call)
    csr_zero_kernel<<<(Vc + 255) / 256, 256, 0, stream>>>(cnt);
    csr_count_kernel<<<(2 * Ec + 255) / 256, 256, 0, stream>>>(src, dst, cnt);
    csr_scan_kernel<<<1, 256, 0, stream>>>(cnt, off, cur);
    csr_fill_kernel<<<(2 * Ec + 255) / 256, 256, 0, stream>>>(src, dst, cur, adj);

    const int vblocks = (Bc * Vc + 63) / 64;   // 2 waves x 32 vertices
    const int eblocks = (Bc * Ec + 63) / 64;   // 2 waves x 32 edges
    for (int i = 0; i < Lc; ++i) {
        gather_kernel<<<(Bc * Vc + 3) / 4, 256, 0, stream>>>(h, off, adj, vf);
        vertex_gemm_kernel<<<vblocks, 128, 0, stream>>>(
            vf, w1af + (size_t)i * 32768, b1 + i * Dc, yA, yB);
        edge_layer_kernel<<<eblocks, 128, 0, stream>>>(
            h, yA, yB, src, dst,
            ln_g + i * Dc, ln_b + i * Dc,
            w2f + (size_t)i * 16384, b2 + i * Dc,
            ng + i * Dc, nb + i * Dc,
            (i == Lc - 1) ? w_out : nullptr, b_out, out);
    }
}